// Round 1
// baseline (1369.093 us; speedup 1.0000x reference)
//
#include <hip/hip_runtime.h>
#include <math.h>

#define B_DIM 4
#define C_DIM 256
#define N_DIM 2048
#define H_DIM 8
#define HD    64

// ---------------------------------------------------------------------------
// Projection: Z = W (O x C) @ X[b] (C x N) (+ bias), stored as (h,b,n,d)
// with h = o>>6, d = o&63.  64x64 output tile per block, 16x16 threads x 4x4.
// ---------------------------------------------------------------------------
__global__ __launch_bounds__(256) void proj_kernel(
    const float* __restrict__ X,     // (B, C, N)
    const float* __restrict__ W,     // (O, C)
    const float* __restrict__ bias,  // (O) or nullptr
    float* __restrict__ out)         // (O/64, B, N, 64)
{
    const int b  = blockIdx.z;
    const int o0 = blockIdx.y * 64;
    const int n0 = blockIdx.x * 64;

    __shared__ float Wl[16][65];  // [cc][o]
    __shared__ float Xl[16][65];  // [cc][n]

    const int t  = threadIdx.x;
    const int tn = t & 15;        // n-subtile
    const int to = t >> 4;        // o-subtile

    float acc[4][4];
#pragma unroll
    for (int a = 0; a < 4; ++a)
#pragma unroll
        for (int c = 0; c < 4; ++c) acc[a][c] = 0.f;

    for (int c0 = 0; c0 < C_DIM; c0 += 16) {
#pragma unroll
        for (int i = 0; i < 4; ++i) {
            int idx = t + i * 256;
            int oo = idx >> 4, cc = idx & 15;
            Wl[cc][oo] = W[(size_t)(o0 + oo) * C_DIM + c0 + cc];
            int cc2 = idx >> 6, nn = idx & 63;
            Xl[cc2][nn] = X[((size_t)b * C_DIM + c0 + cc2) * N_DIM + n0 + nn];
        }
        __syncthreads();
#pragma unroll
        for (int cc = 0; cc < 16; ++cc) {
            float wr[4], xr[4];
#pragma unroll
            for (int j = 0; j < 4; ++j) { wr[j] = Wl[cc][to * 4 + j]; xr[j] = Xl[cc][tn * 4 + j]; }
#pragma unroll
            for (int jo = 0; jo < 4; ++jo)
#pragma unroll
                for (int jn = 0; jn < 4; ++jn)
                    acc[jo][jn] = fmaf(wr[jo], xr[jn], acc[jo][jn]);
        }
        __syncthreads();
    }

#pragma unroll
    for (int jo = 0; jo < 4; ++jo) {
        int o = o0 + to * 4 + jo;
        float bv = bias ? bias[o] : 0.f;
        int h = o >> 6, d = o & 63;
#pragma unroll
        for (int jn = 0; jn < 4; ++jn) {
            int n = n0 + tn * 4 + jn;
            out[(((size_t)h * B_DIM + b) * N_DIM + n) * HD + d] = acc[jo][jn] + bv;
        }
    }
}

// ---------------------------------------------------------------------------
// Pass A: per-row softmax stats. For each (hb, n): rowmax = max_m Q[n].K[m],
// rowsum = sum_m exp(e - rowmax). Online over 64-wide m tiles.
// ---------------------------------------------------------------------------
__global__ __launch_bounds__(256) void rowstats_kernel(
    const float* __restrict__ Q, const float* __restrict__ K,
    float* __restrict__ rowmax, float* __restrict__ rowsum)
{
    const int hb = blockIdx.y;
    const int n0 = blockIdx.x * 64;
    const float* Qb = Q + (size_t)hb * N_DIM * HD;
    const float* Kb = K + (size_t)hb * N_DIM * HD;

    __shared__ float Ql[64][65];
    __shared__ float Kl[64][65];
    __shared__ float red_m[64][17];
    __shared__ float red_s[64][17];

    const int t = threadIdx.x;
    for (int i = t; i < 4096; i += 256) {
        int r = i >> 6, c = i & 63;
        Ql[r][c] = Qb[(size_t)(n0 + r) * HD + c];
    }

    const int tn = t & 15, tm = t >> 4;
    float mx[4], sm[4];
#pragma unroll
    for (int j = 0; j < 4; ++j) { mx[j] = -INFINITY; sm[j] = 0.f; }

    for (int m0 = 0; m0 < N_DIM; m0 += 64) {
        for (int i = t; i < 4096; i += 256) {
            int r = i >> 6, c = i & 63;
            Kl[r][c] = Kb[(size_t)(m0 + r) * HD + c];
        }
        __syncthreads();

        float acc[4][4];
#pragma unroll
        for (int a = 0; a < 4; ++a)
#pragma unroll
            for (int c = 0; c < 4; ++c) acc[a][c] = 0.f;

#pragma unroll 8
        for (int d = 0; d < 64; ++d) {
            float q[4], k[4];
#pragma unroll
            for (int j = 0; j < 4; ++j) { q[j] = Ql[tn * 4 + j][d]; k[j] = Kl[tm * 4 + j][d]; }
#pragma unroll
            for (int jn = 0; jn < 4; ++jn)
#pragma unroll
                for (int jm = 0; jm < 4; ++jm)
                    acc[jn][jm] = fmaf(q[jn], k[jm], acc[jn][jm]);
        }

#pragma unroll
        for (int jn = 0; jn < 4; ++jn) {
            float tmax = fmaxf(fmaxf(acc[jn][0], acc[jn][1]), fmaxf(acc[jn][2], acc[jn][3]));
            float nm = fmaxf(mx[jn], tmax);
            float s = __expf(acc[jn][0] - nm) + __expf(acc[jn][1] - nm) +
                      __expf(acc[jn][2] - nm) + __expf(acc[jn][3] - nm);
            sm[jn] = sm[jn] * __expf(mx[jn] - nm) + s;
            mx[jn] = nm;
        }
        __syncthreads();
    }

#pragma unroll
    for (int jn = 0; jn < 4; ++jn) {
        red_m[tn * 4 + jn][tm] = mx[jn];
        red_s[tn * 4 + jn][tm] = sm[jn];
    }
    __syncthreads();
    if (t < 64) {
        float M = -INFINITY;
#pragma unroll
        for (int i = 0; i < 16; ++i) M = fmaxf(M, red_m[t][i]);
        float S = 0.f;
#pragma unroll
        for (int i = 0; i < 16; ++i) S += red_s[t][i] * __expf(red_m[t][i] - M);
        rowmax[(size_t)hb * N_DIM + n0 + t] = M;
        rowsum[(size_t)hb * N_DIM + n0 + t] = S;
    }
}

// ---------------------------------------------------------------------------
// Pass B: out[m,d] = sum_n p[n,m] * V[n,d], p = exp(Q[n].K[m] - rowmax[n]) / rowsum[n]
// then blend: out = (g*out + yp) / (1+g). One 64-wide m tile per block.
// ---------------------------------------------------------------------------
__global__ __launch_bounds__(256) void attnout_kernel(
    const float* __restrict__ Q, const float* __restrict__ K, const float* __restrict__ V,
    const float* __restrict__ rowmax, const float* __restrict__ rowsum,
    const float* __restrict__ YP,     // (B, N, HD)
    const float* __restrict__ gamma,  // (H)
    float* __restrict__ out)          // (H, B, N, HD)
{
    const int hb = blockIdx.y;
    const int h = hb / B_DIM, b = hb % B_DIM;
    const int m0 = blockIdx.x * 64;
    const float* Qb = Q + (size_t)hb * N_DIM * HD;
    const float* Kb = K + (size_t)hb * N_DIM * HD;
    const float* Vb = V + (size_t)hb * N_DIM * HD;

    __shared__ float Kl[64][65];
    __shared__ float Ql[64][65];
    __shared__ float Vl[64][65];
    __shared__ float Pl[64][65];
    __shared__ float Rm[64], Rs[64];

    const int t = threadIdx.x;
    for (int i = t; i < 4096; i += 256) {
        int r = i >> 6, c = i & 63;
        Kl[r][c] = Kb[(size_t)(m0 + r) * HD + c];
    }

    const int tn = t & 15, tm = t >> 4;
    float oacc[4][4];  // [jm][jd]: m = tn*4+jm, d = tm*4+jd
#pragma unroll
    for (int a = 0; a < 4; ++a)
#pragma unroll
        for (int c = 0; c < 4; ++c) oacc[a][c] = 0.f;

    for (int n0 = 0; n0 < N_DIM; n0 += 64) {
        for (int i = t; i < 4096; i += 256) {
            int r = i >> 6, c = i & 63;
            Ql[r][c] = Qb[(size_t)(n0 + r) * HD + c];
            Vl[r][c] = Vb[(size_t)(n0 + r) * HD + c];
        }
        if (t < 64) {
            Rm[t] = rowmax[(size_t)hb * N_DIM + n0 + t];
            Rs[t] = rowsum[(size_t)hb * N_DIM + n0 + t];
        }
        __syncthreads();

        // phase 1: e[n][m] tile; n from tn, m from tm
        float acc[4][4];
#pragma unroll
        for (int a = 0; a < 4; ++a)
#pragma unroll
            for (int c = 0; c < 4; ++c) acc[a][c] = 0.f;

#pragma unroll 8
        for (int d = 0; d < 64; ++d) {
            float q[4], k[4];
#pragma unroll
            for (int j = 0; j < 4; ++j) { q[j] = Ql[tn * 4 + j][d]; k[j] = Kl[tm * 4 + j][d]; }
#pragma unroll
            for (int jn = 0; jn < 4; ++jn)
#pragma unroll
                for (int jm = 0; jm < 4; ++jm)
                    acc[jn][jm] = fmaf(q[jn], k[jm], acc[jn][jm]);
        }
#pragma unroll
        for (int jn = 0; jn < 4; ++jn) {
            float rm = Rm[tn * 4 + jn];
            float ri = 1.f / Rs[tn * 4 + jn];
#pragma unroll
            for (int jm = 0; jm < 4; ++jm)
                Pl[tn * 4 + jn][tm * 4 + jm] = __expf(acc[jn][jm] - rm) * ri;
        }
        __syncthreads();

        // phase 2: out[m][d] += P[n][m] * V[n][d]; m from tn, d from tm
#pragma unroll 8
        for (int n = 0; n < 64; ++n) {
            float p[4], v[4];
#pragma unroll
            for (int j = 0; j < 4; ++j) { p[j] = Pl[n][tn * 4 + j]; v[j] = Vl[n][tm * 4 + j]; }
#pragma unroll
            for (int jm = 0; jm < 4; ++jm)
#pragma unroll
                for (int jd = 0; jd < 4; ++jd)
                    oacc[jm][jd] = fmaf(p[jm], v[jd], oacc[jm][jd]);
        }
        __syncthreads();
    }

    const float g = gamma[h];
    const float inv = 1.f / (1.f + g);
#pragma unroll
    for (int jm = 0; jm < 4; ++jm) {
        int m = m0 + tn * 4 + jm;
        const size_t obase = (((size_t)h * B_DIM + b) * N_DIM + m) * HD;
        const size_t ybase = ((size_t)b * N_DIM + m) * HD;
#pragma unroll
        for (int jd = 0; jd < 4; ++jd) {
            int d = tm * 4 + jd;
            out[obase + d] = (g * oacc[jm][jd] + YP[ybase + d]) * inv;
        }
    }
}

// ---------------------------------------------------------------------------
extern "C" void kernel_launch(void* const* d_in, const int* in_sizes, int n_in,
                              void* d_out, int out_size, void* d_ws, size_t ws_size,
                              hipStream_t stream) {
    const float* x     = (const float*)d_in[0];
    const float* y     = (const float*)d_in[1];
    const float* Wq    = (const float*)d_in[2];
    const float* bq    = (const float*)d_in[3];
    const float* Wk    = (const float*)d_in[4];
    const float* bk    = (const float*)d_in[5];
    const float* Wv    = (const float*)d_in[6];
    const float* bv    = (const float*)d_in[7];
    const float* Wp    = (const float*)d_in[8];
    const float* gamma = (const float*)d_in[9];
    float* out = (float*)d_out;

    float* ws = (float*)d_ws;
    const size_t QKV = (size_t)H_DIM * B_DIM * N_DIM * HD;  // 4,194,304
    float* Qb = ws;
    float* Kb = Qb + QKV;
    float* Vb = Kb + QKV;
    float* YP = Vb + QKV;                                   // B*N*HD = 524,288
    float* RM = YP + (size_t)B_DIM * N_DIM * HD;            // H*B*N = 65,536
    float* RS = RM + (size_t)H_DIM * B_DIM * N_DIM;

    dim3 blk(256);
    proj_kernel<<<dim3(N_DIM / 64, 8, B_DIM), blk, 0, stream>>>(x, Wq, bq, Qb);
    proj_kernel<<<dim3(N_DIM / 64, 8, B_DIM), blk, 0, stream>>>(y, Wk, bk, Kb);
    proj_kernel<<<dim3(N_DIM / 64, 8, B_DIM), blk, 0, stream>>>(y, Wv, bv, Vb);
    proj_kernel<<<dim3(N_DIM / 64, 1, B_DIM), blk, 0, stream>>>(y, Wp, nullptr, YP);

    rowstats_kernel<<<dim3(N_DIM / 64, H_DIM * B_DIM), blk, 0, stream>>>(Qb, Kb, RM, RS);

    attnout_kernel<<<dim3(N_DIM / 64, H_DIM * B_DIM), blk, 0, stream>>>(
        Qb, Kb, Vb, RM, RS, YP, gamma, out);
}

// Round 2
// 593.283 us; speedup vs baseline: 2.3077x; 2.3077x over previous
//
#include <hip/hip_runtime.h>
#include <math.h>

#define B_DIM 4
#define C_DIM 256
#define N_DIM 2048
#define H_DIM 8
#define HD    64

typedef __attribute__((ext_vector_type(8))) short bf16x8;
typedef __attribute__((ext_vector_type(4))) float f32x4;

static __device__ __forceinline__ short f2bf(float f) {
    unsigned u = __builtin_bit_cast(unsigned, f);
    u += 0x7fffu + ((u >> 16) & 1u);
    return (short)(u >> 16);
}

// ---------------------------------------------------------------------------
// Projection: Z = W (O x C) @ X[b] (C x N) (+ bias), fp32 compute.
// mode 0: bf16 out (h,b,n,d);  mode 1: bf16 out transposed (h,b,d,n);
// mode 2: fp32 out (b,n,d)  [h must be 0].
// ---------------------------------------------------------------------------
__global__ __launch_bounds__(256) void proj_kernel(
    const float* __restrict__ X,     // (B, C, N)
    const float* __restrict__ W,     // (O, C)
    const float* __restrict__ bias,  // (O) or nullptr
    void* __restrict__ outp, int mode)
{
    const int b  = blockIdx.z;
    const int o0 = blockIdx.y * 64;
    const int n0 = blockIdx.x * 64;

    __shared__ float Wl[16][65];  // [cc][o]
    __shared__ float Xl[16][65];  // [cc][n]

    const int t  = threadIdx.x;
    const int tn = t & 15;
    const int to = t >> 4;

    float acc[4][4];
#pragma unroll
    for (int a = 0; a < 4; ++a)
#pragma unroll
        for (int c = 0; c < 4; ++c) acc[a][c] = 0.f;

    for (int c0 = 0; c0 < C_DIM; c0 += 16) {
#pragma unroll
        for (int i = 0; i < 4; ++i) {
            int idx = t + i * 256;
            int oo = idx >> 4, cc = idx & 15;
            Wl[cc][oo] = W[(size_t)(o0 + oo) * C_DIM + c0 + cc];
            int cc2 = idx >> 6, nn = idx & 63;
            Xl[cc2][nn] = X[((size_t)b * C_DIM + c0 + cc2) * N_DIM + n0 + nn];
        }
        __syncthreads();
#pragma unroll
        for (int cc = 0; cc < 16; ++cc) {
            float wr[4], xr[4];
#pragma unroll
            for (int j = 0; j < 4; ++j) { wr[j] = Wl[cc][to * 4 + j]; xr[j] = Xl[cc][tn * 4 + j]; }
#pragma unroll
            for (int jo = 0; jo < 4; ++jo)
#pragma unroll
                for (int jn = 0; jn < 4; ++jn)
                    acc[jo][jn] = fmaf(wr[jo], xr[jn], acc[jo][jn]);
        }
        __syncthreads();
    }

#pragma unroll
    for (int jo = 0; jo < 4; ++jo) {
        int o = o0 + to * 4 + jo;
        float bv = bias ? bias[o] : 0.f;
        int h = o >> 6, d = o & 63;
#pragma unroll
        for (int jn = 0; jn < 4; ++jn) {
            int n = n0 + tn * 4 + jn;
            float v = acc[jo][jn] + bv;
            if (mode == 0) {
                ((short*)outp)[(((size_t)h * B_DIM + b) * N_DIM + n) * HD + d] = f2bf(v);
            } else if (mode == 1) {
                ((short*)outp)[(((size_t)h * B_DIM + b) * HD + d) * N_DIM + n] = f2bf(v);
            } else {
                ((float*)outp)[((size_t)b * N_DIM + n) * HD + d] = v;
            }
        }
    }
}

// ---------------------------------------------------------------------------
// Pass A: per-row softmax stats via bf16 MFMA. Block = (hb, 64-row n-tile).
// Wave w owns rows [16w,16w+16). No LDS, no barriers.
// C/D layout (16x16x32): row = quad*4+reg, col = lane&15.
// A layout: A[m=lane&15][k=quad*8+j];  B (as Bt): Bt[n=lane&15][k=quad*8+j].
// ---------------------------------------------------------------------------
__global__ __launch_bounds__(256) void rowstats_mfma(
    const short* __restrict__ Q, const short* __restrict__ K,
    float* __restrict__ rowmax, float* __restrict__ rowsum)
{
    const int hb = blockIdx.y;
    const int n0 = blockIdx.x * 64;
    const int t = threadIdx.x;
    const int wave = t >> 6, lane = t & 63;
    const int lo = lane & 15, quad = lane >> 4;

    // A = Q rows (fixed per wave): Q[n0+16w+lo][quad*8 + j + 32*dstep]
    const short* qp = Q + ((size_t)hb * N_DIM + n0 + wave * 16 + lo) * HD + quad * 8;
    const bf16x8 a0 = *(const bf16x8*)qp;
    const bf16x8 a1 = *(const bf16x8*)(qp + 32);

    float mx[4], sm[4];
#pragma unroll
    for (int r = 0; r < 4; ++r) { mx[r] = -INFINITY; sm[r] = 0.f; }

    const short* kbase = K + (size_t)hb * N_DIM * HD + quad * 8;
    for (int m0 = 0; m0 < N_DIM; m0 += 64) {
        float e[4][4];
#pragma unroll
        for (int mt = 0; mt < 4; ++mt) {
            const short* kp = kbase + (size_t)(m0 + mt * 16 + lo) * HD;
            bf16x8 b0 = *(const bf16x8*)kp;
            bf16x8 b1 = *(const bf16x8*)(kp + 32);
            f32x4 c = {0.f, 0.f, 0.f, 0.f};
            c = __builtin_amdgcn_mfma_f32_16x16x32_bf16(a0, b0, c, 0, 0, 0);
            c = __builtin_amdgcn_mfma_f32_16x16x32_bf16(a1, b1, c, 0, 0, 0);
#pragma unroll
            for (int r = 0; r < 4; ++r) e[mt][r] = c[r];
        }
#pragma unroll
        for (int r = 0; r < 4; ++r) {
            float tm = fmaxf(fmaxf(e[0][r], e[1][r]), fmaxf(e[2][r], e[3][r]));
            float nm = fmaxf(mx[r], tm);
            float s = __expf(e[0][r] - nm) + __expf(e[1][r] - nm) +
                      __expf(e[2][r] - nm) + __expf(e[3][r] - nm);
            sm[r] = sm[r] * __expf(mx[r] - nm) + s;
            mx[r] = nm;
        }
    }

    // reduce across the 16 lanes (lo) that share each row
#pragma unroll
    for (int s = 1; s < 16; s <<= 1) {
#pragma unroll
        for (int r = 0; r < 4; ++r) {
            float om = __shfl_xor(mx[r], s);
            float os = __shfl_xor(sm[r], s);
            float nm = fmaxf(mx[r], om);
            sm[r] = sm[r] * __expf(mx[r] - nm) + os * __expf(om - nm);
            mx[r] = nm;
        }
    }
    if (lo == 0) {
        int row = n0 + wave * 16 + quad * 4;
#pragma unroll
        for (int r = 0; r < 4; ++r) {
            rowmax[(size_t)hb * N_DIM + row + r] = mx[r];
            rowsum[(size_t)hb * N_DIM + row + r] = sm[r];
        }
    }
}

// ---------------------------------------------------------------------------
// Pass B: out[m,d] = sum_n P[n,m] V[n,d];  P = exp(E - rm[n]) / rs[n].
// Block = (hb, 64-m window). Wave w owns m rows [16w,16w+16).
// Main loop has NO barriers: each wave writes/reads only its own P rows.
// ---------------------------------------------------------------------------
__global__ __launch_bounds__(256) void attnout_mfma(
    const short* __restrict__ Q, const short* __restrict__ K,
    const short* __restrict__ Vt,   // (hb, d, n) bf16
    const float* __restrict__ rowmax, const float* __restrict__ rowsum,
    const float* __restrict__ YP,   // (B, N, HD) fp32
    const float* __restrict__ gamma,
    float* __restrict__ out)        // (H, B, N, HD) fp32
{
    const int hb = blockIdx.y;
    const int h = hb >> 2, b = hb & 3;
    const int m0 = blockIdx.x * 64;

    __shared__ float Rm[N_DIM];
    __shared__ float Ri[N_DIM];
    __shared__ short Pl[64][72];   // [m][n] bf16, stride 72 (144B: 16B-aligned, 2-way free)

    const int t = threadIdx.x;
    for (int i = t; i < N_DIM; i += 256) {
        Rm[i] = rowmax[(size_t)hb * N_DIM + i];
        Ri[i] = 1.f / rowsum[(size_t)hb * N_DIM + i];
    }

    const int wave = t >> 6, lane = t & 63;
    const int lo = lane & 15, quad = lane >> 4;

    // K fragments (B of QK), fixed per block: K[m0+16w+lo][dstep*32+quad*8+j]
    const short* kp = K + ((size_t)hb * N_DIM + m0 + wave * 16 + lo) * HD + quad * 8;
    const bf16x8 bk0 = *(const bf16x8*)kp;
    const bf16x8 bk1 = *(const bf16x8*)(kp + 32);

    f32x4 oacc[4];
#pragma unroll
    for (int dt = 0; dt < 4; ++dt) oacc[dt] = (f32x4){0.f, 0.f, 0.f, 0.f};

    const short* qbase = Q + (size_t)hb * N_DIM * HD + quad * 8;
    const short* vbase = Vt + (size_t)hb * HD * N_DIM + quad * 8;
    short* prow = &Pl[wave * 16 + lo][0];

    __syncthreads();  // Rm/Ri ready

    for (int n0 = 0; n0 < N_DIM; n0 += 64) {
        // ---- QK: E[n][m] for n in [n0,n0+64), m in wave's 16-window ----
#pragma unroll
        for (int nt = 0; nt < 4; ++nt) {
            const short* qp2 = qbase + (size_t)(n0 + nt * 16 + lo) * HD;
            bf16x8 a0 = *(const bf16x8*)qp2;
            bf16x8 a1 = *(const bf16x8*)(qp2 + 32);
            f32x4 c = {0.f, 0.f, 0.f, 0.f};
            c = __builtin_amdgcn_mfma_f32_16x16x32_bf16(a0, bk0, c, 0, 0, 0);
            c = __builtin_amdgcn_mfma_f32_16x16x32_bf16(a1, bk1, c, 0, 0, 0);
            // c[r] = E[n = n0+nt*16+quad*4+r][m = m0+wave*16+lo]
            int nb = n0 + nt * 16 + quad * 4;
            short4 pk;
            pk.x = f2bf(__expf(c[0] - Rm[nb + 0]) * Ri[nb + 0]);
            pk.y = f2bf(__expf(c[1] - Rm[nb + 1]) * Ri[nb + 1]);
            pk.z = f2bf(__expf(c[2] - Rm[nb + 2]) * Ri[nb + 2]);
            pk.w = f2bf(__expf(c[3] - Rm[nb + 3]) * Ri[nb + 3]);
            *(short4*)(prow + nt * 16 + quad * 4) = pk;  // Pl[m][n'] b64 write
        }
        // ---- PV: oacc[m][d] += P^T[m][n] * V[n][d] ----
#pragma unroll
        for (int ks = 0; ks < 2; ++ks) {
            bf16x8 ap = *(const bf16x8*)(prow + ks * 32 + quad * 8);  // ds_read_b128
#pragma unroll
            for (int dt = 0; dt < 4; ++dt) {
                const short* vp = vbase + (size_t)(dt * 16 + lo) * N_DIM + n0 + ks * 32;
                bf16x8 bv = *(const bf16x8*)vp;
                oacc[dt] = __builtin_amdgcn_mfma_f32_16x16x32_bf16(ap, bv, oacc[dt], 0, 0, 0);
            }
        }
    }

    const float g = gamma[h];
    const float inv = 1.f / (1.f + g);
#pragma unroll
    for (int dt = 0; dt < 4; ++dt) {
        int d = dt * 16 + lo;
#pragma unroll
        for (int r = 0; r < 4; ++r) {
            int m = m0 + wave * 16 + quad * 4 + r;
            out[((size_t)hb * N_DIM + m) * HD + d] =
                (g * oacc[dt][r] + YP[((size_t)b * N_DIM + m) * HD + d]) * inv;
        }
    }
}

// ---------------------------------------------------------------------------
extern "C" void kernel_launch(void* const* d_in, const int* in_sizes, int n_in,
                              void* d_out, int out_size, void* d_ws, size_t ws_size,
                              hipStream_t stream) {
    const float* x     = (const float*)d_in[0];
    const float* y     = (const float*)d_in[1];
    const float* Wq    = (const float*)d_in[2];
    const float* bq    = (const float*)d_in[3];
    const float* Wk    = (const float*)d_in[4];
    const float* bk    = (const float*)d_in[5];
    const float* Wv    = (const float*)d_in[6];
    const float* bv    = (const float*)d_in[7];
    const float* Wp    = (const float*)d_in[8];
    const float* gamma = (const float*)d_in[9];
    float* out = (float*)d_out;

    const size_t QKV = (size_t)H_DIM * B_DIM * N_DIM * HD;  // 4,194,304 elems
    short* Qb16 = (short*)d_ws;
    short* Kb16 = Qb16 + QKV;
    short* Vt16 = Kb16 + QKV;
    float* YP   = (float*)(Vt16 + QKV);
    float* RM   = YP + (size_t)B_DIM * N_DIM * HD;
    float* RS   = RM + (size_t)H_DIM * B_DIM * N_DIM;

    dim3 blk(256);
    proj_kernel<<<dim3(N_DIM / 64, 8, B_DIM), blk, 0, stream>>>(x, Wq, bq, Qb16, 0);
    proj_kernel<<<dim3(N_DIM / 64, 8, B_DIM), blk, 0, stream>>>(y, Wk, bk, Kb16, 0);
    proj_kernel<<<dim3(N_DIM / 64, 8, B_DIM), blk, 0, stream>>>(y, Wv, bv, Vt16, 1);
    proj_kernel<<<dim3(N_DIM / 64, 1, B_DIM), blk, 0, stream>>>(y, Wp, nullptr, YP, 2);

    rowstats_mfma<<<dim3(N_DIM / 64, H_DIM * B_DIM), blk, 0, stream>>>(Qb16, Kb16, RM, RS);

    attnout_mfma<<<dim3(N_DIM / 64, H_DIM * B_DIM), blk, 0, stream>>>(
        Qb16, Kb16, Vt16, RM, RS, YP, gamma, out);
}